// Round 8
// baseline (153.728 us; speedup 1.0000x reference)
//
#include <hip/hip_runtime.h>
#include <math.h>

// Capsule routing, fused. B=64, I=1024, O=1024 fp32.
//
// Math reduction: routing state collapses to c_k = softmax_o(u*w*vsum), so
// no [B,I,O] tensor is ever materialized.
//
// R6/R7 equilibrium: spill-free via amdgpu_waves_per_eu(4,4) + unroll 2;
// block = 4 waves x same i-range, wave owns b; parallel reduce_squash.
// R8: stage_k read w TWICE per wave from global (pass A + pass B), and the
// block's 4 waves read identical addresses -> 8x redundant L1 traffic
// (~2MB/CU/stage = ~13.6us at 64B/cyc). Now: stage each 8-i w tile (32KB)
// into LDS ONCE per block via global_load_lds (width 16, wave-uniform
// base + lane*16), both passes ds_read_b128 it. LDS 32KB/block x 4
// blocks/CU = 128KB <= 160KB.

#define BB 64
#define II 1024
#define OO 1024
#define EPSF 1e-5f
#define LOG2E 1.44269504088896340736f

__device__ __forceinline__ float wave_sum(float v) {
    #pragma unroll
    for (int off = 32; off > 0; off >>= 1)
        v += __shfl_xor(v, off, 64);
    return v;
}
__device__ __forceinline__ float rfl(float x) {  // force SGPR broadcast
    return __int_as_float(__builtin_amdgcn_readfirstlane(__float_as_int(x)));
}

// ---------------- stage kernel ----------------
// grid = (BB/4) * IBLKS, block = 256. wave -> b = bg*4+wave.
// lane owns o = j*256 + lane*4 + e  (j,e in 0..3).
template<int IBLKS>
__global__ __launch_bounds__(256)
__attribute__((amdgpu_waves_per_eu(4, 4)))
void stage_k(
    const float* __restrict__ u, const float* __restrict__ w,
    const float* __restrict__ v, float* __restrict__ part)
{
    constexpr int IPB = II / IBLKS;   // i's per block (= per wave)
    constexpr int NG  = IPB / 8;      // groups of 8 i's
    static_assert(IPB % 8 == 0, "need groups of 8");
    const int bg   = blockIdx.x / IBLKS;
    const int iblk = blockIdx.x % IBLKS;
    const int wave = threadIdx.x >> 6;
    const int lane = threadIdx.x & 63;
    const int b    = bg * 4 + wave;
    const float4* w4 = (const float4*)w;
    const float4* v4 = (const float4*)(v + b * OO);

    // One group's w tile: 8 i-rows x 1024 o = 32 KB.
    __shared__ float4 wt[8 * 256];

    // v pre-scaled by log2e so logits feed v_exp_f32 directly.
    float vv[16];
    #pragma unroll
    for (int j = 0; j < 4; j++) {
        float4 a = v4[j * 64 + lane];
        vv[j*4+0]=a.x*LOG2E; vv[j*4+1]=a.y*LOG2E;
        vv[j*4+2]=a.z*LOG2E; vv[j*4+3]=a.w*LOG2E;
    }
    float ar[16];
    #pragma unroll
    for (int k = 0; k < 16; k++) ar[k] = 0.f;

    const int i0 = iblk * IPB;
    #pragma unroll 1
    for (int g = 0; g < NG; g++) {
        const int ib = i0 + g * 8;

        // ---- stage w tile to LDS: 32 chunks of 1KB; wave wv takes
        // chunks p = wv*8+k (ii = p>>2 row, c = p&3 quarter-row).
        // LDS dest = wt + p*64 (wave-uniform) + lane*16 (implicit). ----
        if (g > 0) __syncthreads();     // protect previous tile's readers
        #pragma unroll
        for (int k = 0; k < 8; k++) {
            const int p  = wave * 8 + k;
            const int ii = p >> 2, c = p & 3;
            const float4* gp = w4 + (size_t)(ib + ii) * 256 + c * 64 + lane;
            __builtin_amdgcn_global_load_lds(
                (const __attribute__((address_space(1))) void*)gp,
                (__attribute__((address_space(3))) void*)(&wt[p * 64]),
                16, 0, 0);
        }
        // u values -> SGPRs (wave-uniform loads; overlap with staging)
        float us[8];
        #pragma unroll
        for (int ii = 0; ii < 8; ii++)
            us[ii] = rfl(u[b * II + ib + ii]);
        __syncthreads();                // drains vmcnt + joins 4 waves

        // ---- pass A: per-lane partial denominators (no cross-lane ops) ----
        float sA[8];
        #pragma unroll 2
        for (int ii = 0; ii < 8; ii++) {
            float a0;
            {
                float4 t = wt[ii * 256 + 0 * 64 + lane];
                a0 = __builtin_amdgcn_exp2f((t.x * vv[0]) * us[ii])
                   + __builtin_amdgcn_exp2f((t.y * vv[1]) * us[ii])
                   + __builtin_amdgcn_exp2f((t.z * vv[2]) * us[ii])
                   + __builtin_amdgcn_exp2f((t.w * vv[3]) * us[ii]);
            }
            #pragma unroll
            for (int j = 1; j < 4; j++) {
                float4 t = wt[ii * 256 + j * 64 + lane];
                a0 += __builtin_amdgcn_exp2f((t.x * vv[j*4+0]) * us[ii])
                    + __builtin_amdgcn_exp2f((t.y * vv[j*4+1]) * us[ii])
                    + __builtin_amdgcn_exp2f((t.z * vv[j*4+2]) * us[ii])
                    + __builtin_amdgcn_exp2f((t.w * vv[j*4+3]) * us[ii]);
            }
            sA[ii] = a0;
        }
        // ---- one batched butterfly: 6 layers x 8 independent chains ----
        #pragma unroll
        for (int off = 32; off > 0; off >>= 1) {
            #pragma unroll
            for (int ii = 0; ii < 8; ii++)
                sA[ii] += __shfl_xor(sA[ii], off, 64);
        }
        // q = u * rcp(denom) -> SGPRs
        float qs[8];
        #pragma unroll
        for (int ii = 0; ii < 8; ii++)
            qs[ii] = rfl(us[ii] * __builtin_amdgcn_rcpf(sA[ii]));

        // ---- pass B: re-read LDS tile, accumulate ----
        #pragma unroll 2
        for (int ii = 0; ii < 8; ii++) {
            #pragma unroll
            for (int j = 0; j < 4; j++) {
                float4 t = wt[ii * 256 + j * 64 + lane];
                float p;
                p = __builtin_amdgcn_exp2f((t.x * vv[j*4+0]) * us[ii]);
                ar[j*4+0] = fmaf(t.x * p, qs[ii], ar[j*4+0]);
                p = __builtin_amdgcn_exp2f((t.y * vv[j*4+1]) * us[ii]);
                ar[j*4+1] = fmaf(t.y * p, qs[ii], ar[j*4+1]);
                p = __builtin_amdgcn_exp2f((t.z * vv[j*4+2]) * us[ii]);
                ar[j*4+2] = fmaf(t.z * p, qs[ii], ar[j*4+2]);
                p = __builtin_amdgcn_exp2f((t.w * vv[j*4+3]) * us[ii]);
                ar[j*4+3] = fmaf(t.w * p, qs[ii], ar[j*4+3]);
            }
        }
    }
    // direct coalesced partial store: each wave owns its (b, iblk) slice
    float4* dst = (float4*)(part + ((size_t)iblk * BB + b) * OO);
    #pragma unroll
    for (int j = 0; j < 4; j++) {
        float4 o;
        o.x = ar[j*4+0]; o.y = ar[j*4+1]; o.z = ar[j*4+2]; o.w = ar[j*4+3];
        dst[j * 64 + lane] = o;
    }
}

// ---------------- partial GEMM (same block structure, single pass) -------
template<int IBLKS>
__global__ __launch_bounds__(256)
__attribute__((amdgpu_waves_per_eu(4, 4)))
void gemm_k(
    const float* __restrict__ u, const float* __restrict__ w,
    float* __restrict__ part)
{
    constexpr int IPB = II / IBLKS;
    const int bg   = blockIdx.x / IBLKS;
    const int iblk = blockIdx.x % IBLKS;
    const int wave = threadIdx.x >> 6;
    const int lane = threadIdx.x & 63;
    const int b    = bg * 4 + wave;
    const float4* w4 = (const float4*)w;

    float ar[16];
    #pragma unroll
    for (int k = 0; k < 16; k++) ar[k] = 0.f;

    const int i0 = iblk * IPB;
    #pragma unroll 2
    for (int ii = 0; ii < IPB; ii++) {
        const int i = i0 + ii;
        const float ub = rfl(u[b * II + i]);
        #pragma unroll
        for (int j = 0; j < 4; j++) {
            float4 t = w4[i * 256 + j * 64 + lane];
            ar[j*4+0] = fmaf(ub, t.x, ar[j*4+0]);
            ar[j*4+1] = fmaf(ub, t.y, ar[j*4+1]);
            ar[j*4+2] = fmaf(ub, t.z, ar[j*4+2]);
            ar[j*4+3] = fmaf(ub, t.w, ar[j*4+3]);
        }
    }
    float4* dst = (float4*)(part + ((size_t)iblk * BB + b) * OO);
    #pragma unroll
    for (int j = 0; j < 4; j++) {
        float4 o;
        o.x = ar[j*4+0]; o.y = ar[j*4+1]; o.z = ar[j*4+2]; o.w = ar[j*4+3];
        dst[j * 64 + lane] = o;
    }
}

// ---------------- reduce + squash ----------------
// 1024 threads: thread (sl = t>>8, qd = t&255) sums slices
// [sl*nblk/4, (sl+1)*nblk/4) of o-quad qd; 16KB LDS float4 tree; squash
// epilogue on threads<256. mode 0: vbuf=v  1: vbuf+=v  2: out=v
__global__ __launch_bounds__(1024) void reduce_squash(
    const float* __restrict__ part, const float* __restrict__ bias,
    float* __restrict__ vbuf, float* __restrict__ out,
    float scale, int mode, int nblk)
{
    const int b  = blockIdx.x;
    const int t  = threadIdx.x;
    const int qd = t & 255;
    const int sl = t >> 8;
    const int per = nblk >> 2;
    const float4* p4 = (const float4*)part;

    float4 a0 = make_float4(0.f, 0.f, 0.f, 0.f), a1 = a0;
    const int k0 = sl * per;
    #pragma unroll 2
    for (int k = 0; k < per; k += 2) {
        float4 p0 = p4[(size_t)((k0 + k)     * BB + b) * 256 + qd];
        float4 p1 = p4[(size_t)((k0 + k + 1) * BB + b) * 256 + qd];
        a0.x += p0.x; a0.y += p0.y; a0.z += p0.z; a0.w += p0.w;
        a1.x += p1.x; a1.y += p1.y; a1.z += p1.z; a1.w += p1.w;
    }
    a0.x += a1.x; a0.y += a1.y; a0.z += a1.z; a0.w += a1.w;

    __shared__ float4 redq[1024];   // [sl][qd], 16 KB
    redq[t] = a0;
    __syncthreads();

    float ss = 0.f;
    float4 x;
    if (t < 256) {
        float4 r0 = redq[qd], r1 = redq[256 + qd],
               r2 = redq[512 + qd], r3 = redq[768 + qd];
        float4 s;
        s.x = (r0.x + r1.x) + (r2.x + r3.x);
        s.y = (r0.y + r1.y) + (r2.y + r3.y);
        s.z = (r0.z + r1.z) + (r2.z + r3.z);
        s.w = (r0.w + r1.w) + (r2.w + r3.w);
        float4 bb = ((const float4*)bias)[qd];
        x.x = fmaf(s.x, scale, bb.x); x.y = fmaf(s.y, scale, bb.y);
        x.z = fmaf(s.z, scale, bb.z); x.w = fmaf(s.w, scale, bb.w);
        ss = x.x*x.x + x.y*x.y + x.z*x.z + x.w*x.w;
    }
    ss = wave_sum(ss);              // waves 4..15 carry zeros
    __shared__ float red2[16];
    if ((t & 63) == 0) red2[t >> 6] = ss;
    __syncthreads();
    const float tot = (red2[0] + red2[1]) + (red2[2] + red2[3]);

    if (t < 256) {
        const float n = sqrtf(tot);
        const float f = tot / ((1.f + tot) * (n + EPSF));
        float4 vo;
        vo.x = x.x * f; vo.y = x.y * f; vo.z = x.z * f; vo.w = x.w * f;
        if (mode == 0) {
            ((float4*)(vbuf + b * OO))[qd] = vo;
        } else if (mode == 1) {
            float4 pv = ((const float4*)(vbuf + b * OO))[qd];
            pv.x += vo.x; pv.y += vo.y; pv.z += vo.z; pv.w += vo.w;
            ((float4*)(vbuf + b * OO))[qd] = pv;
        } else {
            ((float4*)(out + b * OO))[qd] = vo;
        }
    }
}

template<int IBLKS>
static void run_pipeline(const float* u, const float* w, const float* bias,
                         float* out, void* d_ws, hipStream_t stream)
{
    float* part = (float*)d_ws;
    float* vbuf = part + (size_t)IBLKS * BB * OO;
    dim3 g((BB / 4) * IBLKS), blk(256), rblk(1024);
    // v1 = squash((u@w)/O + bias)
    gemm_k<IBLKS><<<g, blk, 0, stream>>>(u, w, part);
    reduce_squash<<<dim3(BB), rblk, 0, stream>>>(part, bias, vbuf, out,
                                                 1.0f / (float)OO, 0, IBLKS);
    // vsum = v1 + squash(s2 + bias),  s2 via softmax(u*w*v1)
    stage_k<IBLKS><<<g, blk, 0, stream>>>(u, w, vbuf, part);
    reduce_squash<<<dim3(BB), rblk, 0, stream>>>(part, bias, vbuf, out,
                                                 1.0f, 1, IBLKS);
    // out = squash(s3 + bias),  s3 via softmax(u*w*vsum)
    stage_k<IBLKS><<<g, blk, 0, stream>>>(u, w, vbuf, part);
    reduce_squash<<<dim3(BB), rblk, 0, stream>>>(part, bias, vbuf, out,
                                                 1.0f, 2, IBLKS);
}

extern "C" void kernel_launch(void* const* d_in, const int* in_sizes, int n_in,
                              void* d_out, int out_size, void* d_ws, size_t ws_size,
                              hipStream_t stream) {
    (void)in_sizes; (void)n_in; (void)out_size;
    const float* u    = (const float*)d_in[0];
    const float* w    = (const float*)d_in[1];
    const float* bias = (const float*)d_in[2];
    float* out = (float*)d_out;

    const size_t row = (size_t)BB * OO * sizeof(float);  // 256 KB
    if      (ws_size >= 65 * row) run_pipeline<64>(u, w, bias, out, d_ws, stream);
    else if (ws_size >= 33 * row) run_pipeline<32>(u, w, bias, out, d_ws, stream);
    else if (ws_size >= 17 * row) run_pipeline<16>(u, w, bias, out, d_ws, stream);
    else                          run_pipeline<8>(u, w, bias, out, d_ws, stream);
}